// Round 3
// baseline (1506.372 us; speedup 1.0000x reference)
//
#include <hip/hip_runtime.h>

#define B_    1024
#define T_    512
#define I_    16
#define H_    50
#define FC_   64
#define QW    14    // quarter of padded H (56)
#define HP    56

typedef float v2f __attribute__((ext_vector_type(2)));

__device__ __forceinline__ float frcp(float x)   { return __builtin_amdgcn_rcpf(x); }
__device__ __forceinline__ float sigm(float x)   { return frcp(1.0f + __expf(-x)); }
__device__ __forceinline__ float tanh_f(float x) { return 1.0f - 2.0f * frcp(1.0f + __expf(2.0f * x)); }
__device__ __forceinline__ v2f   fma2(v2f a, v2f b, v2f c) { return __builtin_elementwise_fma(a, b, c); }
__device__ __forceinline__ v2f   mk2(float a, float b) { v2f r; r.x = a; r.y = b; return r; }

// quad-local DPP adds for the 4-way s-join (VALU pipe, no DS)
__device__ __forceinline__ float dpp_xor1(float v) {   // swap (0,1),(2,3)
    return __int_as_float(__builtin_amdgcn_update_dpp(0, __float_as_int(v), 0xB1, 0xF, 0xF, true));
}
__device__ __forceinline__ float dpp_xor2(float v) {   // swap (0,2),(1,3)
    return __int_as_float(__builtin_amdgcn_update_dpp(0, __float_as_int(v), 0x4E, 0xF, 0xF, true));
}
// lane^4 exchange for the gate-pair swap (DS swizzle, 1 inst)
__device__ __forceinline__ float swz4(float v) {
    return __int_as_float(__builtin_amdgcn_ds_swizzle(__float_as_int(v), 0x101F)); // xor-mask 4
}

// 1 batch row per block, 2 gates per lane, 4-way H split.
// tid = 8*u + 4*qp + s  (u = unit 0..49, qp = gate pair {i,f}/{g,o}, s = dot quarter)
// Per-lane weights: 46 v2f = 92 VGPRs -> total ~122 regs -> 16 waves/CU budget,
// 2 blocks/CU resident with independent barriers (stall phases interleave).
__global__ __launch_bounds__(448, 4) void lstm_q4(
    const float* __restrict__ x,
    const float* __restrict__ w_ih0, const float* __restrict__ w_hh0,
    const float* __restrict__ b_ih0, const float* __restrict__ b_hh0,
    const float* __restrict__ w_ih1, const float* __restrict__ w_hh1,
    const float* __restrict__ b_ih1, const float* __restrict__ b_hh1,
    const float* __restrict__ fc1_w, const float* __restrict__ fc1_b,
    const float* __restrict__ fc2_w, const float* __restrict__ fc2_b,
    float* __restrict__ out)
{
    __shared__ float h0s[2][HP], h1s[2][HP];

    const int tid = threadIdx.x;
    const int u   = tid >> 3;
    const int qp  = (tid >> 2) & 1;
    const int s   = tid & 3;
    const bool gl = tid < 8 * H_;     // 400 working lanes
    const int row = blockIdx.x;

    // activation selectors for gate j=0 (qp0 -> i: sigmoid, qp1 -> g: tanh)
    const float qa = qp ? 2.0f : -1.0f;
    const float qb = qp ? 1.0f :  0.0f;
    const float qm = qp ? -2.0f : 1.0f;

    // ---- persistent packed weights: 46 v2f = 92 floats / lane ----
    v2f w0x[2][2], w0h[2][7], w1x[2][7], w1h[2][7];
    float bias0[2] = {0.f, 0.f}, bias1[2] = {0.f, 0.f};
    if (gl) {
        #pragma unroll
        for (int j = 0; j < 2; ++j) {
            const int g = (2 * qp + j) * H_ + u;
            #pragma unroll
            for (int k = 0; k < 2; ++k)
                w0x[j][k] = mk2(w_ih0[g * I_ + s * 4 + 2 * k],
                                w_ih0[g * I_ + s * 4 + 2 * k + 1]);
            #pragma unroll
            for (int k = 0; k < 7; ++k) {
                const int j0 = s * QW + 2 * k, j1 = j0 + 1;
                const bool v0 = j0 < H_, v1 = j1 < H_;
                w0h[j][k] = mk2(v0 ? w_hh0[g * H_ + j0] : 0.f, v1 ? w_hh0[g * H_ + j1] : 0.f);
                w1x[j][k] = mk2(v0 ? w_ih1[g * H_ + j0] : 0.f, v1 ? w_ih1[g * H_ + j1] : 0.f);
                w1h[j][k] = mk2(v0 ? w_hh1[g * H_ + j0] : 0.f, v1 ? w_hh1[g * H_ + j1] : 0.f);
            }
            if (s == 0) {             // bias enters once per 4-lane join group
                bias0[j] = b_ih0[g] + b_hh0[g];
                bias1[j] = b_ih1[g] + b_hh1[g];
            }
        }
    }

    if (tid < 112) { ((float*)h0s)[tid] = 0.f; ((float*)h1s)[tid] = 0.f; }
    float c0 = 0.f, c1 = 0.f;
    __syncthreads();

    // 4-way join -> activations -> xor4 gate exchange -> cell update
    auto cell = [&](v2f A0, v2f A1, float& c) -> float {
        float p0 = A0.x + A0.y;  p0 += dpp_xor1(p0);  p0 += dpp_xor2(p0);
        float p1 = A1.x + A1.y;  p1 += dpp_xor1(p1);  p1 += dpp_xor2(p1);
        float act0 = qb + qm * frcp(1.0f + __expf(qa * p0));  // i (qp0) or g (qp1)
        float act1 = sigm(p1);                                // f (qp0) or o (qp1)
        float r0 = swz4(act0);
        float r1 = swz4(act1);
        float gi = qp ? r0 : act0;
        float gf = qp ? r1 : act1;
        float gg = qp ? act0 : r0;
        float go = qp ? act1 : r1;
        c = gf * c + gi * gg;
        return go * tanh_f(c);
    };

    // ---- prologue: P0(0), h0_prev = 0 ----
    if (gl) {
        const float4 xv = *(const float4*)(x + (size_t)row * T_ * I_ + s * 4);
        v2f B0 = mk2(bias0[0], 0.f), B1 = mk2(bias0[1], 0.f);
        B0 = fma2(w0x[0][0], mk2(xv.x, xv.y), B0);
        B0 = fma2(w0x[0][1], mk2(xv.z, xv.w), B0);
        B1 = fma2(w0x[1][0], mk2(xv.x, xv.y), B1);
        B1 = fma2(w0x[1][1], mk2(xv.z, xv.w), B1);
        float hv = cell(B0, B1, c0);
        if ((tid & 7) == 0) h0s[0][u] = hv;
    }
    __syncthreads();

    // ---- main loop: one barrier/step; P1(t) fused with P0(t+1) ----
    #pragma unroll 2
    for (int t = 0; t < T_ - 1; ++t) {
        const int pp = t & 1, pn = pp ^ 1;
        if (gl) {
            // x(t+1): issue first, consume last
            const float4 xv = *(const float4*)(x + ((size_t)row * T_ + (t + 1)) * I_ + s * 4);
            const v2f* h0p = (const v2f*)&h0s[pp][s * QW];   // h0 after step t
            const v2f* h1p = (const v2f*)&h1s[pn][s * QW];   // h1 after step t-1
            v2f A0 = mk2(bias1[0], 0.f), A1 = mk2(bias1[1], 0.f);   // layer-1, P1(t)
            v2f B0 = mk2(bias0[0], 0.f), B1 = mk2(bias0[1], 0.f);   // layer-0, P0(t+1)
            #pragma unroll
            for (int k = 0; k < 7; ++k) {          // shared h0 read feeds 4 pk_fma
                v2f hv = h0p[k];
                A0 = fma2(w1x[0][k], hv, A0);  A1 = fma2(w1x[1][k], hv, A1);
                B0 = fma2(w0h[0][k], hv, B0);  B1 = fma2(w0h[1][k], hv, B1);
            }
            #pragma unroll
            for (int k = 0; k < 7; ++k) {
                v2f hv = h1p[k];
                A0 = fma2(w1h[0][k], hv, A0);  A1 = fma2(w1h[1][k], hv, A1);
            }
            B0 = fma2(w0x[0][0], mk2(xv.x, xv.y), B0);
            B0 = fma2(w0x[0][1], mk2(xv.z, xv.w), B0);
            B1 = fma2(w0x[1][0], mk2(xv.x, xv.y), B1);
            B1 = fma2(w0x[1][1], mk2(xv.z, xv.w), B1);
            float h1v = cell(A0, A1, c1);
            float h0v = cell(B0, B1, c0);
            if ((tid & 7) == 0) { h1s[pp][u] = h1v; h0s[pn][u] = h0v; }
        }
        __syncthreads();
    }

    // ---- epilogue: P1(T-1); final h0 in h0s[1], h1 in h1s[0] ----
    if (gl) {
        const v2f* h0p = (const v2f*)&h0s[1][s * QW];
        const v2f* h1p = (const v2f*)&h1s[0][s * QW];
        v2f A0 = mk2(bias1[0], 0.f), A1 = mk2(bias1[1], 0.f);
        #pragma unroll
        for (int k = 0; k < 7; ++k) {
            v2f hv = h0p[k];
            A0 = fma2(w1x[0][k], hv, A0);  A1 = fma2(w1x[1][k], hv, A1);
        }
        #pragma unroll
        for (int k = 0; k < 7; ++k) {
            v2f hv = h1p[k];
            A0 = fma2(w1h[0][k], hv, A0);  A1 = fma2(w1h[1][k], hv, A1);
        }
        float h1v = cell(A0, A1, c1);
        if ((tid & 7) == 0) h1s[1][u] = h1v;
    }
    __syncthreads();

    // ---- FC epilogue on wave 0 ----
    if (tid < FC_) {
        const float* hf = h1s[1];
        float a = fc1_b[tid];
        #pragma unroll
        for (int j = 0; j < H_; ++j) a += fc1_w[tid * H_ + j] * hf[j];
        float v = fmaxf(a, 0.f) * fc2_w[tid];
        #pragma unroll
        for (int off = 1; off < FC_; off <<= 1) v += __shfl_xor(v, off);
        if (tid == 0) out[row] = v + fc2_b[0];
    }
}

extern "C" void kernel_launch(void* const* d_in, const int* in_sizes, int n_in,
                              void* d_out, int out_size, void* d_ws, size_t ws_size,
                              hipStream_t stream) {
    const float* x     = (const float*)d_in[0];
    const float* w_ih0 = (const float*)d_in[1];
    const float* w_hh0 = (const float*)d_in[2];
    const float* b_ih0 = (const float*)d_in[3];
    const float* b_hh0 = (const float*)d_in[4];
    const float* w_ih1 = (const float*)d_in[5];
    const float* w_hh1 = (const float*)d_in[6];
    const float* b_ih1 = (const float*)d_in[7];
    const float* b_hh1 = (const float*)d_in[8];
    const float* fc1_w = (const float*)d_in[9];
    const float* fc1_b = (const float*)d_in[10];
    const float* fc2_w = (const float*)d_in[11];
    const float* fc2_b = (const float*)d_in[12];
    float* out = (float*)d_out;

    dim3 grid(B_), block(448);
    hipLaunchKernelGGL(lstm_q4, grid, block, 0, stream,
                       x, w_ih0, w_hh0, b_ih0, b_hh0,
                       w_ih1, w_hh1, b_ih1, b_hh1,
                       fc1_w, fc1_b, fc2_w, fc2_b, out);
}

// Round 5
// 1348.597 us; speedup vs baseline: 1.1170x; 1.1170x over previous
//
#include <hip/hip_runtime.h>

#define B_    1024
#define T_    512
#define I_    16
#define H_    50
#define FC_   64
#define HALFW 28    // half of padded H (56)
#define HP    56    // H padded for float4 reads
#define R_    4     // batch rows per thread

typedef float v2f __attribute__((ext_vector_type(2)));

__device__ __forceinline__ float frcp(float x)   { return __builtin_amdgcn_rcpf(x); }
__device__ __forceinline__ float sigm(float x)   { return frcp(1.0f + __expf(-x)); }
__device__ __forceinline__ float tanh_f(float x) { return 1.0f - 2.0f * frcp(1.0f + __expf(2.0f * x)); }
__device__ __forceinline__ v2f   fma2(v2f a, v2f b, v2f c) { return __builtin_elementwise_fma(a, b, c); }
__device__ __forceinline__ v2f   mk2(float a, float b) { v2f r; r.x = a; r.y = b; return r; }

// intra-quad shuffles on the VALU (DPP quad_perm), DS pipe stays free
__device__ __forceinline__ float dpp_xor1(float v) {   // swap (0,1),(2,3)
    return __int_as_float(__builtin_amdgcn_update_dpp(0, __float_as_int(v), 0xB1, 0xF, 0xF, true));
}
__device__ __forceinline__ float dpp_xor2(float v) {   // swap (0,2),(1,3)
    return __int_as_float(__builtin_amdgcn_update_dpp(0, __float_as_int(v), 0x4E, 0xF, 0xF, true));
}

// one float4 of h against packed weight pair -> 2x v_pk_fma_f32
#define PKDOT(acc, W, kk, hv) { acc = fma2(W[2*(kk)],   mk2(hv.x, hv.y), acc); \
                                acc = fma2(W[2*(kk)+1], mk2(hv.z, hv.w), acc); }
// 8-float x segment (two float4) against 4 packed weights
#define XDOT(acc, Wj, v0, v1) { acc = fma2(Wj[0], mk2(v0.x, v0.y), acc); \
                                acc = fma2(Wj[1], mk2(v0.z, v0.w), acc); \
                                acc = fma2(Wj[2], mk2(v1.x, v1.y), acc); \
                                acc = fma2(Wj[3], mk2(v1.z, v1.w), acc); }

// 4 batch rows per thread, 2 gates per lane, 2-way H split (round-2 lane layout).
// tid = 4*u + 2*qp + s. grid = 256 -> 1 block/CU, 1 wave/SIMD: latency hiding is
// pure ILP (16 FMA chains + 8 cell chains). launch_bounds(256,1) -> 512-reg budget,
// the ~250-reg working set (184 weight floats) stays in arch VGPRs with NO spill.
__global__ __launch_bounds__(256, 1) void lstm_r4(
    const float* __restrict__ x,
    const float* __restrict__ w_ih0, const float* __restrict__ w_hh0,
    const float* __restrict__ b_ih0, const float* __restrict__ b_hh0,
    const float* __restrict__ w_ih1, const float* __restrict__ w_hh1,
    const float* __restrict__ b_ih1, const float* __restrict__ b_hh1,
    const float* __restrict__ fc1_w, const float* __restrict__ fc1_b,
    const float* __restrict__ fc2_w, const float* __restrict__ fc2_b,
    float* __restrict__ out)
{
    __shared__ float h0s[2][R_][HP];   // [pingpong][row][HP]
    __shared__ float h1s[2][R_][HP];

    const int tid  = threadIdx.x;
    const int u    = tid >> 2;
    const int qp   = (tid >> 1) & 1;
    const int s    = tid & 1;
    const bool gl  = tid < 4 * H_;    // 200 working lanes
    const int row0 = blockIdx.x * R_;

    // activation selectors for gate j=0 (qp0 -> i: sigmoid, qp1 -> g: tanh)
    const float qa = qp ? 2.0f : -1.0f;
    const float qb = qp ? 1.0f :  0.0f;
    const float qm = qp ? -2.0f : 1.0f;

    // ---- persistent packed weights: 92 v2f = 184 floats / lane ----
    v2f w0x[2][4], w0h[2][14], w1x[2][14], w1h[2][14];
    float bias0[2] = {0.f, 0.f}, bias1[2] = {0.f, 0.f};
    if (gl) {
        #pragma unroll
        for (int j = 0; j < 2; ++j) {
            const int g = (2 * qp + j) * H_ + u;
            #pragma unroll
            for (int k = 0; k < 4; ++k)
                w0x[j][k] = mk2(w_ih0[g * I_ + s * 8 + 2 * k],
                                w_ih0[g * I_ + s * 8 + 2 * k + 1]);
            #pragma unroll
            for (int k = 0; k < 14; ++k) {
                const int j0 = s * HALFW + 2 * k, j1 = j0 + 1;
                const bool v0 = j0 < H_, v1 = j1 < H_;
                w0h[j][k] = mk2(v0 ? w_hh0[g * H_ + j0] : 0.f, v1 ? w_hh0[g * H_ + j1] : 0.f);
                w1x[j][k] = mk2(v0 ? w_ih1[g * H_ + j0] : 0.f, v1 ? w_ih1[g * H_ + j1] : 0.f);
                w1h[j][k] = mk2(v0 ? w_hh1[g * H_ + j0] : 0.f, v1 ? w_hh1[g * H_ + j1] : 0.f);
            }
            if (s == 0) {             // bias counted once per s-pair
                bias0[j] = b_ih0[g] + b_hh0[g];
                bias1[j] = b_ih1[g] + b_hh1[g];
            }
        }
    }

    for (int i = tid; i < 2 * R_ * HP; i += 256) {
        ((float*)h0s)[i] = 0.f; ((float*)h1s)[i] = 0.f;
    }
    float c0[R_] = {0.f, 0.f, 0.f, 0.f}, c1[R_] = {0.f, 0.f, 0.f, 0.f};
    __syncthreads();

    // packed-pair join -> activations -> cell update (c replicated in all 4 quad lanes)
    auto cell = [&](v2f A0, v2f A1, float& c) -> float {
        float p0 = A0.x + A0.y;  p0 += dpp_xor1(p0);
        float p1 = A1.x + A1.y;  p1 += dpp_xor1(p1);
        float act0 = qb + qm * frcp(1.0f + __expf(qa * p0));  // i (qp0) or g (qp1)
        float act1 = sigm(p1);                                // f (qp0) or o (qp1)
        float ox0 = dpp_xor2(act0);
        float ox1 = dpp_xor2(act1);
        float gi = qp ? ox0 : act0;
        float gf = qp ? ox1 : act1;
        float gg = qp ? act0 : ox0;
        float go = qp ? act1 : ox1;
        c = gf * c + gi * gg;
        return go * tanh_f(c);
    };

    // ---- prologue: P0(0), h0_prev = 0 ----
    if (gl) {
        #pragma unroll
        for (int r = 0; r < R_; ++r) {
            const float* xp = x + (size_t)(row0 + r) * T_ * I_ + s * 8;
            float4 xv0 = *(const float4*)xp;
            float4 xv1 = *(const float4*)(xp + 4);
            v2f a0 = mk2(bias0[0], 0.f), a1 = mk2(bias0[1], 0.f);
            XDOT(a0, w0x[0], xv0, xv1);
            XDOT(a1, w0x[1], xv0, xv1);
            float hv = cell(a0, a1, c0[r]);
            if ((tid & 3) == 0) h0s[0][r][u] = hv;
        }
    }
    __syncthreads();

    // ---- main loop: one barrier/step; P1(t) fused with P0(t+1) ----
    #pragma unroll 2
    for (int t = 0; t < T_ - 1; ++t) {
        const int pp = t & 1, pn = pp ^ 1;
        if (gl) {
            float4 xv[R_][2];                        // x(t+1): issue all first, consume last
            #pragma unroll
            for (int r = 0; r < R_; ++r) {
                const float* xp = x + ((size_t)(row0 + r) * T_ + (t + 1)) * I_ + s * 8;
                xv[r][0] = *(const float4*)xp;
                xv[r][1] = *(const float4*)(xp + 4);
            }
            #pragma unroll
            for (int r = 0; r < R_; ++r) {
                const float4* h0p = (const float4*)(&h0s[pp][r][s * HALFW]);  // h0 after step t
                const float4* h1p = (const float4*)(&h1s[pn][r][s * HALFW]);  // h1 after step t-1
                v2f A0 = mk2(bias1[0], 0.f), A1 = mk2(bias1[1], 0.f);   // layer-1, P1(t)
                v2f B0 = mk2(bias0[0], 0.f), B1 = mk2(bias0[1], 0.f);   // layer-0, P0(t+1)
                #pragma unroll
                for (int k = 0; k < 7; ++k) {         // shared h0 read feeds 8 pk_fma
                    float4 hv = h0p[k];
                    PKDOT(A0, w1x[0], k, hv); PKDOT(A1, w1x[1], k, hv);
                    PKDOT(B0, w0h[0], k, hv); PKDOT(B1, w0h[1], k, hv);
                }
                #pragma unroll
                for (int k = 0; k < 7; ++k) {
                    float4 hv = h1p[k];
                    PKDOT(A0, w1h[0], k, hv); PKDOT(A1, w1h[1], k, hv);
                }
                XDOT(B0, w0x[0], xv[r][0], xv[r][1]);   // x(t+1), loads long done
                XDOT(B1, w0x[1], xv[r][0], xv[r][1]);
                float h1v = cell(A0, A1, c1[r]);
                float h0v = cell(B0, B1, c0[r]);
                if ((tid & 3) == 0) { h1s[pp][r][u] = h1v; h0s[pn][r][u] = h0v; }
            }
        }
        __syncthreads();
    }

    // ---- epilogue: P1(T-1); final h0 in h0s[1], h1 in h1s[0] ----
    if (gl) {
        #pragma unroll
        for (int r = 0; r < R_; ++r) {
            const float4* h0p = (const float4*)(&h0s[1][r][s * HALFW]);
            const float4* h1p = (const float4*)(&h1s[0][r][s * HALFW]);
            v2f A0 = mk2(bias1[0], 0.f), A1 = mk2(bias1[1], 0.f);
            #pragma unroll
            for (int k = 0; k < 7; ++k) {
                float4 hv = h0p[k];
                PKDOT(A0, w1x[0], k, hv); PKDOT(A1, w1x[1], k, hv);
            }
            #pragma unroll
            for (int k = 0; k < 7; ++k) {
                float4 hv = h1p[k];
                PKDOT(A0, w1h[0], k, hv); PKDOT(A1, w1h[1], k, hv);
            }
            float h1v = cell(A0, A1, c1[r]);
            if ((tid & 3) == 0) h1s[1][r][u] = h1v;
        }
    }
    __syncthreads();

    // ---- FC epilogue: wave w reduces row w ----
    {
        const int r = tid >> 6, f = tid & 63;
        const float* hf = h1s[1][r];
        float a = fc1_b[f];
        #pragma unroll
        for (int j = 0; j < H_; ++j) a += fc1_w[f * H_ + j] * hf[j];
        float v = fmaxf(a, 0.f) * fc2_w[f];
        #pragma unroll
        for (int off = 1; off < FC_; off <<= 1) v += __shfl_xor(v, off);
        if (f == 0) out[row0 + r] = v + fc2_b[0];
    }
}

extern "C" void kernel_launch(void* const* d_in, const int* in_sizes, int n_in,
                              void* d_out, int out_size, void* d_ws, size_t ws_size,
                              hipStream_t stream) {
    const float* x     = (const float*)d_in[0];
    const float* w_ih0 = (const float*)d_in[1];
    const float* w_hh0 = (const float*)d_in[2];
    const float* b_ih0 = (const float*)d_in[3];
    const float* b_hh0 = (const float*)d_in[4];
    const float* w_ih1 = (const float*)d_in[5];
    const float* w_hh1 = (const float*)d_in[6];
    const float* b_ih1 = (const float*)d_in[7];
    const float* b_hh1 = (const float*)d_in[8];
    const float* fc1_w = (const float*)d_in[9];
    const float* fc1_b = (const float*)d_in[10];
    const float* fc2_w = (const float*)d_in[11];
    const float* fc2_b = (const float*)d_in[12];
    float* out = (float*)d_out;

    dim3 grid(B_ / R_), block(256);
    hipLaunchKernelGGL(lstm_r4, grid, block, 0, stream,
                       x, w_ih0, w_hh0, b_ih0, b_hh0,
                       w_ih1, w_hh1, b_ih1, b_hh1,
                       fc1_w, fc1_b, fc2_w, fc2_b, out);
}

// Round 6
// 970.908 us; speedup vs baseline: 1.5515x; 1.3890x over previous
//
#include <hip/hip_runtime.h>

#define B_    1024
#define T_    512
#define I_    16
#define H_    50
#define FC_   64
#define HALFW 28    // half of padded H (56)
#define HP    56    // H padded for float4 reads
#define R_    2     // batch rows per thread

typedef float v2f __attribute__((ext_vector_type(2)));

__device__ __forceinline__ float frcp(float x)   { return __builtin_amdgcn_rcpf(x); }
__device__ __forceinline__ float sigm(float x)   { return frcp(1.0f + __expf(-x)); }
__device__ __forceinline__ float tanh_f(float x) { return 1.0f - 2.0f * frcp(1.0f + __expf(2.0f * x)); }
__device__ __forceinline__ v2f   fma2(v2f a, v2f b, v2f c) { return __builtin_elementwise_fma(a, b, c); }
__device__ __forceinline__ v2f   mk2(float a, float b) { v2f r; r.x = a; r.y = b; return r; }

// intra-quad shuffles on the VALU (DPP quad_perm), DS pipe stays free
__device__ __forceinline__ float dpp_xor1(float v) {   // swap (0,1),(2,3)
    return __int_as_float(__builtin_amdgcn_update_dpp(0, __float_as_int(v), 0xB1, 0xF, 0xF, true));
}
__device__ __forceinline__ float dpp_xor2(float v) {   // swap (0,2),(1,3)
    return __int_as_float(__builtin_amdgcn_update_dpp(0, __float_as_int(v), 0x4E, 0xF, 0xF, true));
}

// one float4 of h against packed weight pair -> 2x v_pk_fma_f32
#define PKDOT(acc, W, kk, hv) { acc = fma2(W[2*(kk)],   mk2(hv.x, hv.y), acc); \
                                acc = fma2(W[2*(kk)+1], mk2(hv.z, hv.w), acc); }
// 8-float x segment (two float4) against 4 packed weights
#define XDOT(acc, Wj, v0, v1) { acc = fma2(Wj[0], mk2(v0.x, v0.y), acc); \
                                acc = fma2(Wj[1], mk2(v0.z, v0.w), acc); \
                                acc = fma2(Wj[2], mk2(v1.x, v1.y), acc); \
                                acc = fma2(Wj[3], mk2(v1.z, v1.w), acc); }

// 2 rows/thread, 2 gates/lane, 2-way H split. tid = 4*u + 2*qp + s.
// amdgpu_waves_per_eu(2,2) PINS the compiler to a 256-reg budget so the
// ~230-reg working set (184 weight floats) stays in ARCH VGPRs: no AGPR
// round-trips (R5 pathology: VGPR=152 + accvgpr moves = 3x inst inflation),
// no scratch (R2 pathology). grid 512 -> 2 blocks/CU, barriers interleave.
__global__ __launch_bounds__(256) __attribute__((amdgpu_waves_per_eu(2, 2)))
void lstm_r2p(
    const float* __restrict__ x,
    const float* __restrict__ w_ih0, const float* __restrict__ w_hh0,
    const float* __restrict__ b_ih0, const float* __restrict__ b_hh0,
    const float* __restrict__ w_ih1, const float* __restrict__ w_hh1,
    const float* __restrict__ b_ih1, const float* __restrict__ b_hh1,
    const float* __restrict__ fc1_w, const float* __restrict__ fc1_b,
    const float* __restrict__ fc2_w, const float* __restrict__ fc2_b,
    float* __restrict__ out)
{
    __shared__ float h0s[2][R_][HP];   // [pingpong][row][HP]
    __shared__ float h1s[2][R_][HP];

    const int tid  = threadIdx.x;
    const int u    = tid >> 2;
    const int qp   = (tid >> 1) & 1;
    const int s    = tid & 1;
    const bool gl  = tid < 4 * H_;    // 200 working lanes
    const int row0 = blockIdx.x * R_;

    // activation selectors for gate j=0 (qp0 -> i: sigmoid, qp1 -> g: tanh)
    const float qa = qp ? 2.0f : -1.0f;
    const float qb = qp ? 1.0f :  0.0f;
    const float qm = qp ? -2.0f : 1.0f;

    // ---- persistent packed weights: 92 v2f = 184 floats / lane ----
    v2f w0x[2][4], w0h[2][14], w1x[2][14], w1h[2][14];
    float bias0[2] = {0.f, 0.f}, bias1[2] = {0.f, 0.f};
    if (gl) {
        #pragma unroll
        for (int j = 0; j < 2; ++j) {
            const int g = (2 * qp + j) * H_ + u;
            #pragma unroll
            for (int k = 0; k < 4; ++k)
                w0x[j][k] = mk2(w_ih0[g * I_ + s * 8 + 2 * k],
                                w_ih0[g * I_ + s * 8 + 2 * k + 1]);
            #pragma unroll
            for (int k = 0; k < 14; ++k) {
                const int j0 = s * HALFW + 2 * k, j1 = j0 + 1;
                const bool v0 = j0 < H_, v1 = j1 < H_;
                w0h[j][k] = mk2(v0 ? w_hh0[g * H_ + j0] : 0.f, v1 ? w_hh0[g * H_ + j1] : 0.f);
                w1x[j][k] = mk2(v0 ? w_ih1[g * H_ + j0] : 0.f, v1 ? w_ih1[g * H_ + j1] : 0.f);
                w1h[j][k] = mk2(v0 ? w_hh1[g * H_ + j0] : 0.f, v1 ? w_hh1[g * H_ + j1] : 0.f);
            }
            if (s == 0) {             // bias counted once per s-pair
                bias0[j] = b_ih0[g] + b_hh0[g];
                bias1[j] = b_ih1[g] + b_hh1[g];
            }
        }
    }

    if (tid < 2 * R_ * HP) { ((float*)h0s)[tid] = 0.f; ((float*)h1s)[tid] = 0.f; }
    float c0[R_] = {0.f, 0.f}, c1[R_] = {0.f, 0.f};
    __syncthreads();

    // packed-pair join -> activations -> cell update (c replicated in all 4 quad lanes)
    auto cell = [&](v2f A0, v2f A1, float& c) -> float {
        float p0 = A0.x + A0.y;  p0 += dpp_xor1(p0);
        float p1 = A1.x + A1.y;  p1 += dpp_xor1(p1);
        float act0 = qb + qm * frcp(1.0f + __expf(qa * p0));  // i (qp0) or g (qp1)
        float act1 = sigm(p1);                                // f (qp0) or o (qp1)
        float ox0 = dpp_xor2(act0);
        float ox1 = dpp_xor2(act1);
        float gi = qp ? ox0 : act0;
        float gf = qp ? ox1 : act1;
        float gg = qp ? act0 : ox0;
        float go = qp ? act1 : ox1;
        c = gf * c + gi * gg;
        return go * tanh_f(c);
    };

    // ---- prologue: P0(0), h0_prev = 0 ----
    if (gl) {
        #pragma unroll
        for (int r = 0; r < R_; ++r) {
            const float* xp = x + (size_t)(row0 + r) * T_ * I_ + s * 8;
            float4 xv0 = *(const float4*)xp;
            float4 xv1 = *(const float4*)(xp + 4);
            v2f a0 = mk2(bias0[0], 0.f), a1 = mk2(bias0[1], 0.f);
            XDOT(a0, w0x[0], xv0, xv1);
            XDOT(a1, w0x[1], xv0, xv1);
            float hv = cell(a0, a1, c0[r]);
            if ((tid & 3) == 0) h0s[0][r][u] = hv;
        }
    }
    __syncthreads();

    // ---- main loop: one barrier/step; P1(t) fused with P0(t+1) ----
    #pragma unroll 2
    for (int t = 0; t < T_ - 1; ++t) {
        const int pp = t & 1, pn = pp ^ 1;
        if (gl) {
            float4 xv[R_][2];                        // x(t+1): issue all first, consume last
            #pragma unroll
            for (int r = 0; r < R_; ++r) {
                const float* xp = x + ((size_t)(row0 + r) * T_ + (t + 1)) * I_ + s * 8;
                xv[r][0] = *(const float4*)xp;
                xv[r][1] = *(const float4*)(xp + 4);
            }
            #pragma unroll
            for (int r = 0; r < R_; ++r) {
                const float4* h0p = (const float4*)(&h0s[pp][r][s * HALFW]);  // h0 after step t
                const float4* h1p = (const float4*)(&h1s[pn][r][s * HALFW]);  // h1 after step t-1
                v2f A0 = mk2(bias1[0], 0.f), A1 = mk2(bias1[1], 0.f);   // layer-1, P1(t)
                v2f B0 = mk2(bias0[0], 0.f), B1 = mk2(bias0[1], 0.f);   // layer-0, P0(t+1)
                #pragma unroll
                for (int k = 0; k < 7; ++k) {         // shared h0 read feeds 8 pk_fma
                    float4 hv = h0p[k];
                    PKDOT(A0, w1x[0], k, hv); PKDOT(A1, w1x[1], k, hv);
                    PKDOT(B0, w0h[0], k, hv); PKDOT(B1, w0h[1], k, hv);
                }
                #pragma unroll
                for (int k = 0; k < 7; ++k) {
                    float4 hv = h1p[k];
                    PKDOT(A0, w1h[0], k, hv); PKDOT(A1, w1h[1], k, hv);
                }
                XDOT(B0, w0x[0], xv[r][0], xv[r][1]);   // x(t+1), loads long done
                XDOT(B1, w0x[1], xv[r][0], xv[r][1]);
                float h1v = cell(A0, A1, c1[r]);
                float h0v = cell(B0, B1, c0[r]);
                if ((tid & 3) == 0) { h1s[pp][r][u] = h1v; h0s[pn][r][u] = h0v; }
            }
        }
        __syncthreads();
    }

    // ---- epilogue: P1(T-1); final h0 in h0s[1], h1 in h1s[0] ----
    if (gl) {
        #pragma unroll
        for (int r = 0; r < R_; ++r) {
            const float4* h0p = (const float4*)(&h0s[1][r][s * HALFW]);
            const float4* h1p = (const float4*)(&h1s[0][r][s * HALFW]);
            v2f A0 = mk2(bias1[0], 0.f), A1 = mk2(bias1[1], 0.f);
            #pragma unroll
            for (int k = 0; k < 7; ++k) {
                float4 hv = h0p[k];
                PKDOT(A0, w1x[0], k, hv); PKDOT(A1, w1x[1], k, hv);
            }
            #pragma unroll
            for (int k = 0; k < 7; ++k) {
                float4 hv = h1p[k];
                PKDOT(A0, w1h[0], k, hv); PKDOT(A1, w1h[1], k, hv);
            }
            float h1v = cell(A0, A1, c1[r]);
            if ((tid & 3) == 0) h1s[1][r][u] = h1v;
        }
    }
    __syncthreads();

    // ---- FC epilogue: wave r reduces row r ----
    if (tid < R_ * FC_) {
        const int r = tid >> 6, f = tid & 63;
        const float* hf = h1s[1][r];
        float a = fc1_b[f];
        #pragma unroll
        for (int j = 0; j < H_; ++j) a += fc1_w[f * H_ + j] * hf[j];
        float v = fmaxf(a, 0.f) * fc2_w[f];
        #pragma unroll
        for (int off = 1; off < FC_; off <<= 1) v += __shfl_xor(v, off);
        if (f == 0) out[row0 + r] = v + fc2_b[0];
    }
}

extern "C" void kernel_launch(void* const* d_in, const int* in_sizes, int n_in,
                              void* d_out, int out_size, void* d_ws, size_t ws_size,
                              hipStream_t stream) {
    const float* x     = (const float*)d_in[0];
    const float* w_ih0 = (const float*)d_in[1];
    const float* w_hh0 = (const float*)d_in[2];
    const float* b_ih0 = (const float*)d_in[3];
    const float* b_hh0 = (const float*)d_in[4];
    const float* w_ih1 = (const float*)d_in[5];
    const float* w_hh1 = (const float*)d_in[6];
    const float* b_ih1 = (const float*)d_in[7];
    const float* b_hh1 = (const float*)d_in[8];
    const float* fc1_w = (const float*)d_in[9];
    const float* fc1_b = (const float*)d_in[10];
    const float* fc2_w = (const float*)d_in[11];
    const float* fc2_b = (const float*)d_in[12];
    float* out = (float*)d_out;

    dim3 grid(B_ / R_), block(256);
    hipLaunchKernelGGL(lstm_r2p, grid, block, 0, stream,
                       x, w_ih0, w_hh0, b_ih0, b_hh0,
                       w_ih1, w_hh1, b_ih1, b_hh1,
                       fc1_w, fc1_b, fc2_w, fc2_b, out);
}